// Round 4
// baseline (139.488 us; speedup 1.0000x reference)
//
#include <hip/hip_runtime.h>
#include <hip/hip_bf16.h>
#include <hip/hip_cooperative_groups.h>

namespace cg = cooperative_groups;

// Problem constants (from reference)
#define BATCH    4096
#define IN_DIM   256
#define OUT_DIM  512
#define KDIM     512       // concat K: [silu(x) | spline(x)]
#define NKNOTS   64
#define NBASIS   60        // NUM_KNOTS - DEGREE - 1

typedef __attribute__((ext_vector_type(8))) short bf16x8;   // 8 bf16 in 4 VGPRs
typedef __attribute__((ext_vector_type(4))) float f32x4;

__device__ __forceinline__ short f2bf(float f) {
    __hip_bfloat16 h = __float2bfloat16(f);
    return *reinterpret_cast<short*>(&h);
}
__device__ __forceinline__ float bf2f(short s) {
    __hip_bfloat16 h = *reinterpret_cast<__hip_bfloat16*>(&s);
    return __bfloat162float(h);
}

#define GLOAD_LDS16(g, l)                                                  \
    __builtin_amdgcn_global_load_lds(                                      \
        (const __attribute__((address_space(1))) void*)(g),                \
        (__attribute__((address_space(3))) void*)(l), 16, 0, 0)

// ---------------------------------------------------------------------------
// Single cooperative kernel, 512 blocks x 256 threads.
//   Phase 1 (all blocks): A[b,0:256]=silu(x), A[b,256:512]=spline(x) (bf16),
//       8 batch-rows per block; cps staged transposed in LDS (bf16).
//       Blocks 0..63 additionally transpose one 64x64 tile of wb/ws -> Bt.
//   grid.sync()
//   Phase 2 (all blocks): 64x64 C-tile GEMM via global_load_lds + XOR-swizzled
//       LDS + mfma_f32_16x16x32_bf16 (verbatim R3-verified code).
// LDS union: [0,32K) cpsT (phase1) / also covers the 16.6K transpose tile
// (used before cpsT staging, separated by barriers); [32K,48K) As+Bs (phase2).
// ---------------------------------------------------------------------------
__global__ __launch_bounds__(256) void fused_kernel(
        const float* __restrict__ x, const float* __restrict__ wb,
        const float* __restrict__ ws, const float* __restrict__ cps,
        const float* __restrict__ knots,
        short* __restrict__ A, short* __restrict__ Bt,
        float* __restrict__ C) {
    __shared__ __align__(16) char shmem[49152];          // 48 KB
    short* cpsT = (short*)shmem;                         // [64][256] bf16, 32 KB
    float* tile = (float*)shmem;                         // [64][65] fp32, 16.6 KB
    short* As   = (short*)(shmem + 32768);               // 8 KB
    short* Bs   = (short*)(shmem + 40960);               // 8 KB

    const int tid = threadIdx.x;
    const int bid = blockIdx.x;
    const int lane = tid & 63;
    const int wave = tid >> 6;

    // ================= Phase 1a: B transpose (blocks 0..63) =================
    if (bid < 64) {
        const float* W = (bid & 32) ? ws : wb;           // bid>>5: which matrix
        int koffs = (bid & 32) ? IN_DIM : 0;
        int kb = ((bid >> 3) & 3) * 64;                  // k-tile base, <256
        int nb = (bid & 7) * 64;                         // n-tile base

        for (int it = 0; it < 16; ++it) {
            int f = it * 256 + tid;
            int r = f >> 6, c = f & 63;                  // r: k-row, c: n-col
            tile[r * 65 + c] = W[(kb + r) * OUT_DIM + nb + c];
        }
        __syncthreads();
        for (int it = 0; it < 16; ++it) {
            int f = it * 256 + tid;
            int n = f >> 6, k = f & 63;                  // consecutive k -> coalesced
            Bt[(nb + n) * KDIM + koffs + kb + k] = f2bf(tile[k * 65 + n]);
        }
        __syncthreads();   // tile region about to be overwritten by cpsT
    }

    // ================= Phase 1b: stage cpsT, compute A ======================
    for (int k4 = 0; k4 < NKNOTS; k4 += 4) {
        float4 v = *(const float4*)&cps[tid * NKNOTS + k4];
        cpsT[(k4 + 0) * IN_DIM + tid] = f2bf(v.x);
        cpsT[(k4 + 1) * IN_DIM + tid] = f2bf(v.y);
        cpsT[(k4 + 2) * IN_DIM + tid] = f2bf(v.z);
        cpsT[(k4 + 3) * IN_DIM + tid] = f2bf(v.w);
    }
    __syncthreads();

    // 1M elements / 512 blocks = 2048 per block = 8 per thread
    for (int it = 0; it < 8; ++it) {
        int e = bid * 2048 + it * 256 + tid;             // = b*IN_DIM + i
        int b = e >> 8;
        int i = e & (IN_DIM - 1);

        float xv = x[e];
        float base = xv / (1.0f + __expf(-xv));

        float u = (xv + 1.0f) * 31.5f;                   // 31.5 = 1/h, h = 2/63
        int   j = (int)floorf(u);
        float spline = 0.0f;
        if (j >= 0 && j <= 62) {
            float t  = (xv - knots[j]) * 31.5f;
            float t2 = t * t, t3 = t2 * t;
            float omt = 1.0f - t;
            const float c6 = 1.0f / 6.0f;
            float w0 = omt * omt * omt * c6;                       // k=j-3
            float w1 = (3.0f*t3 - 6.0f*t2 + 4.0f) * c6;            // k=j-2
            float w2 = (-3.0f*t3 + 3.0f*t2 + 3.0f*t + 1.0f) * c6;  // k=j-1
            float w3 = t3 * c6;                                    // k=j
            int k0 = j - 3;
            if (k0     >= 0 && k0     < NBASIS) spline += w0 * bf2f(cpsT[(k0    ) * IN_DIM + i]);
            if (k0 + 1 >= 0 && k0 + 1 < NBASIS) spline += w1 * bf2f(cpsT[(k0 + 1) * IN_DIM + i]);
            if (k0 + 2 >= 0 && k0 + 2 < NBASIS) spline += w2 * bf2f(cpsT[(k0 + 2) * IN_DIM + i]);
            if (k0 + 3 >= 0 && k0 + 3 < NBASIS) spline += w3 * bf2f(cpsT[(k0 + 3) * IN_DIM + i]);
        }
        A[b * KDIM + i]          = f2bf(base);
        A[b * KDIM + IN_DIM + i] = f2bf(spline);
    }

    // ================= grid-wide barrier ====================================
    cg::this_grid().sync();

    // ================= Phase 2: GEMM (verbatim R3-verified) =================
    const int m0 = (bid >> 3) * 64;
    const int n0 = (bid & 7) * 64;
    const int wm = (wave & 1) * 32;        // wave's 32x32 quadrant
    const int wn = (wave >> 1) * 32;
    const int fr = lane & 15;
    const int q  = lane >> 4;              // 0..3

    // staging geometry: 1KB wave-chunk = 8 rows x 8 slots of 16B;
    // data chunk c stored at slot s = c ^ (row&7)
    const int lrow = lane >> 3;            // 0..7
    const int c_sw = (lane & 7) ^ lrow;    // source k-chunk for this lane
    const int ra0 = wave * 16 + lrow;
    const int ra1 = wave * 16 + 8 + lrow;

    f32x4 acc[2][2] = {};

    for (int k0 = 0; k0 < KDIM; k0 += 64) {
        GLOAD_LDS16(&A [(m0 + ra0) * KDIM + k0 + c_sw * 8], &As[(wave * 2    ) * 512]);
        GLOAD_LDS16(&A [(m0 + ra1) * KDIM + k0 + c_sw * 8], &As[(wave * 2 + 1) * 512]);
        GLOAD_LDS16(&Bt[(n0 + ra0) * KDIM + k0 + c_sw * 8], &Bs[(wave * 2    ) * 512]);
        GLOAD_LDS16(&Bt[(n0 + ra1) * KDIM + k0 + c_sw * 8], &Bs[(wave * 2 + 1) * 512]);
        __syncthreads();

        #pragma unroll
        for (int kk = 0; kk < 2; ++kk) {
            const int ck = kk * 4 + q;               // k-chunk index 0..7
            const int sw = (ck ^ (fr & 7)) * 8;      // swizzled slot offset
            bf16x8 a0 = *(const bf16x8*)&As[(wm + fr)      * 64 + sw];
            bf16x8 a1 = *(const bf16x8*)&As[(wm + 16 + fr) * 64 + sw];
            bf16x8 b0 = *(const bf16x8*)&Bs[(wn + fr)      * 64 + sw];
            bf16x8 b1 = *(const bf16x8*)&Bs[(wn + 16 + fr) * 64 + sw];
            acc[0][0] = __builtin_amdgcn_mfma_f32_16x16x32_bf16(a0, b0, acc[0][0], 0, 0, 0);
            acc[0][1] = __builtin_amdgcn_mfma_f32_16x16x32_bf16(a0, b1, acc[0][1], 0, 0, 0);
            acc[1][0] = __builtin_amdgcn_mfma_f32_16x16x32_bf16(a1, b0, acc[1][0], 0, 0, 0);
            acc[1][1] = __builtin_amdgcn_mfma_f32_16x16x32_bf16(a1, b1, acc[1][1], 0, 0, 0);
        }
        __syncthreads();
    }

    // epilogue: C/D layout col = lane&15, row = (lane>>4)*4 + reg  [m89]
    const int rbase = q * 4;
    #pragma unroll
    for (int mt = 0; mt < 2; ++mt) {
        #pragma unroll
        for (int nt = 0; nt < 2; ++nt) {
            #pragma unroll
            for (int r = 0; r < 4; ++r) {
                int row = m0 + wm + mt * 16 + rbase + r;
                int col = n0 + wn + nt * 16 + fr;
                C[row * OUT_DIM + col] = acc[mt][nt][r];
            }
        }
    }
}

// ---------------------------------------------------------------------------
extern "C" void kernel_launch(void* const* d_in, const int* in_sizes, int n_in,
                              void* d_out, int out_size, void* d_ws, size_t ws_size,
                              hipStream_t stream) {
    const float* x     = (const float*)d_in[0];
    const float* wb    = (const float*)d_in[1];
    const float* ws    = (const float*)d_in[2];
    const float* cps   = (const float*)d_in[3];
    const float* knots = (const float*)d_in[4];
    float* out = (float*)d_out;

    short* Abf = (short*)d_ws;                                     // 4 MB
    short* Btb = (short*)((char*)d_ws + (size_t)BATCH * KDIM * 2); // 0.5 MB

    void* args[] = {(void*)&x, (void*)&wb, (void*)&ws, (void*)&cps,
                    (void*)&knots, (void*)&Abf, (void*)&Btb, (void*)&out};
    hipLaunchCooperativeKernel((const void*)fused_kernel, dim3(512), dim3(256),
                               args, 0, stream);
}

// Round 5
// 84.717 us; speedup vs baseline: 1.6465x; 1.6465x over previous
//
#include <hip/hip_runtime.h>
#include <hip/hip_bf16.h>

// Problem constants (from reference)
#define BATCH    4096
#define IN_DIM   256
#define OUT_DIM  512
#define KDIM     512       // concat K: [silu(x) | spline(x)]
#define NKNOTS   64
#define NBASIS   60        // NUM_KNOTS - DEGREE - 1

typedef __attribute__((ext_vector_type(8))) short bf16x8;   // 8 bf16 in 4 VGPRs
typedef __attribute__((ext_vector_type(4))) float f32x4;

__device__ __forceinline__ short f2bf(float f) {
    __hip_bfloat16 h = __float2bfloat16(f);
    return *reinterpret_cast<short*>(&h);
}
__device__ __forceinline__ float bf2f(short s) {
    __hip_bfloat16 h = *reinterpret_cast<__hip_bfloat16*>(&s);
    return __bfloat162float(h);
}

// ---------------------------------------------------------------------------
// Fused prep kernel (R3-verified).
//   blocks [0,256):   A[b,0:256]=silu(x), A[b,256:512]=spline(x)  (bf16)
//   blocks [256,320): Bt[n,k] = concat(wb,ws)^T in bf16 via LDS-tile transpose
// NOTE (R4 evidence): the timed window is dominated by the harness's 268 MB
// d_ws re-poison fills (~84 us at HBM ceiling); regular kernels overlap with
// them (R1 naive == R3 optimized == 84.x us). Cooperative launch serializes
// against the fills (R4: 84 + 55 = 139 us) — do NOT use cooperative here.
// ---------------------------------------------------------------------------
__global__ __launch_bounds__(256) void prep_kernel(
        const float* __restrict__ x, const float* __restrict__ wb,
        const float* __restrict__ ws, const float* __restrict__ cps,
        const float* __restrict__ knots,
        short* __restrict__ A, short* __restrict__ Bt) {
    __shared__ short cpsT[NKNOTS * IN_DIM];   // cpsT[k*256 + i], 32 KB
    __shared__ float tile[64 * 65];           // B-transpose tile, 16.6 KB

    const int tid = threadIdx.x;
    const int bid = blockIdx.x;

    if (bid < 256) {
        // ---- stage cps transposed: thread tid owns input row i = tid ----
        for (int k4 = 0; k4 < NKNOTS; k4 += 4) {
            float4 v = *(const float4*)&cps[tid * NKNOTS + k4];
            cpsT[(k4 + 0) * IN_DIM + tid] = f2bf(v.x);
            cpsT[(k4 + 1) * IN_DIM + tid] = f2bf(v.y);
            cpsT[(k4 + 2) * IN_DIM + tid] = f2bf(v.z);
            cpsT[(k4 + 3) * IN_DIM + tid] = f2bf(v.w);
        }
        __syncthreads();

        // ---- 1M elements / 256 blocks / 256 threads = 16 per thread ----
        for (int it = 0; it < 16; ++it) {
            int e = (bid * 16 + it) * 256 + tid;   // = b*IN_DIM + i
            int b = e >> 8;
            int i = e & (IN_DIM - 1);

            float xv = x[e];
            float base = xv / (1.0f + __expf(-xv));

            float u = (xv + 1.0f) * 31.5f;         // 31.5 = 1/h, h = 2/63
            int   j = (int)floorf(u);
            float spline = 0.0f;
            if (j >= 0 && j <= 62) {
                float t  = (xv - knots[j]) * 31.5f;
                float t2 = t * t, t3 = t2 * t;
                float omt = 1.0f - t;
                const float c6 = 1.0f / 6.0f;
                float w0 = omt * omt * omt * c6;                       // k=j-3
                float w1 = (3.0f*t3 - 6.0f*t2 + 4.0f) * c6;            // k=j-2
                float w2 = (-3.0f*t3 + 3.0f*t2 + 3.0f*t + 1.0f) * c6;  // k=j-1
                float w3 = t3 * c6;                                    // k=j
                int k0 = j - 3;
                if (k0     >= 0 && k0     < NBASIS) spline += w0 * bf2f(cpsT[(k0    ) * IN_DIM + i]);
                if (k0 + 1 >= 0 && k0 + 1 < NBASIS) spline += w1 * bf2f(cpsT[(k0 + 1) * IN_DIM + i]);
                if (k0 + 2 >= 0 && k0 + 2 < NBASIS) spline += w2 * bf2f(cpsT[(k0 + 2) * IN_DIM + i]);
                if (k0 + 3 >= 0 && k0 + 3 < NBASIS) spline += w3 * bf2f(cpsT[(k0 + 3) * IN_DIM + i]);
            }
            A[b * KDIM + i]          = f2bf(base);
            A[b * KDIM + IN_DIM + i] = f2bf(spline);
        }
    } else {
        // ---- B transpose: 64 blocks, 64x64 tile each ----
        int t = bid - 256;                       // 0..63
        const float* W = (t & 32) ? ws : wb;     // t>>5: which matrix
        int koffs = (t & 32) ? IN_DIM : 0;
        int kb = ((t >> 3) & 3) * 64;            // k-tile base, 0..192 (<256)
        int nb = (t & 7) * 64;                   // n-tile base, 0..448

        for (int it = 0; it < 16; ++it) {
            int f = it * 256 + tid;
            int r = f >> 6, c = f & 63;          // r: k-row, c: n-col
            tile[r * 65 + c] = W[(kb + r) * OUT_DIM + nb + c];
        }
        __syncthreads();
        for (int it = 0; it < 16; ++it) {
            int f = it * 256 + tid;
            int n = f >> 6, k = f & 63;          // lanes: consecutive k -> coalesced
            Bt[(nb + n) * KDIM + koffs + kb + k] = f2bf(tile[k * 65 + n]);
        }
    }
}

// ---------------------------------------------------------------------------
// GEMM: C[4096,512] = A @ Bt^T.  64x64 tile, BK=64, 4 waves of 32x32.
// Staging via global_load_lds width=16 (wave-uniform LDS base + lane*16),
// XOR chunk swizzle (slot = chunk ^ (row&7)).
// ---------------------------------------------------------------------------
#define BM 64
#define BN 64
#define BK 64

#define GLOAD_LDS16(g, l)                                                  \
    __builtin_amdgcn_global_load_lds(                                      \
        (const __attribute__((address_space(1))) void*)(g),                \
        (__attribute__((address_space(3))) void*)(l), 16, 0, 0)

__global__ __launch_bounds__(256) void gemm_kernel(
        const short* __restrict__ A, const short* __restrict__ Bt,
        float* __restrict__ C) {
    __shared__ __align__(16) short As[BM * BK];   // 8 KB, swizzled chunks
    __shared__ __align__(16) short Bs[BN * BK];   // 8 KB

    const int tid  = threadIdx.x;
    const int lane = tid & 63;
    const int wave = tid >> 6;
    const int m0 = blockIdx.y * BM;
    const int n0 = blockIdx.x * BN;
    const int wm = (wave & 1) * 32;    // wave's 32x32 quadrant
    const int wn = (wave >> 1) * 32;
    const int fr = lane & 15;
    const int q  = lane >> 4;          // 0..3

    // staging geometry: 1KB wave-chunk = 8 rows x 8 slots of 16B;
    // data chunk c stored at slot s = c ^ (row&7)
    const int lrow = lane >> 3;            // 0..7
    const int c_sw = (lane & 7) ^ lrow;    // source k-chunk for this lane
    const int ra0 = wave * 16 + lrow;
    const int ra1 = wave * 16 + 8 + lrow;

    f32x4 acc[2][2] = {};

    for (int k0 = 0; k0 < KDIM; k0 += BK) {
        GLOAD_LDS16(&A [(m0 + ra0) * KDIM + k0 + c_sw * 8], &As[(wave * 2    ) * 512]);
        GLOAD_LDS16(&A [(m0 + ra1) * KDIM + k0 + c_sw * 8], &As[(wave * 2 + 1) * 512]);
        GLOAD_LDS16(&Bt[(n0 + ra0) * KDIM + k0 + c_sw * 8], &Bs[(wave * 2    ) * 512]);
        GLOAD_LDS16(&Bt[(n0 + ra1) * KDIM + k0 + c_sw * 8], &Bs[(wave * 2 + 1) * 512]);
        __syncthreads();

        #pragma unroll
        for (int kk = 0; kk < 2; ++kk) {
            const int ck = kk * 4 + q;               // k-chunk index 0..7
            const int sw = (ck ^ (fr & 7)) * 8;      // swizzled slot offset
            bf16x8 a0 = *(const bf16x8*)&As[(wm + fr)      * BK + sw];
            bf16x8 a1 = *(const bf16x8*)&As[(wm + 16 + fr) * BK + sw];
            bf16x8 b0 = *(const bf16x8*)&Bs[(wn + fr)      * BK + sw];
            bf16x8 b1 = *(const bf16x8*)&Bs[(wn + 16 + fr) * BK + sw];
            acc[0][0] = __builtin_amdgcn_mfma_f32_16x16x32_bf16(a0, b0, acc[0][0], 0, 0, 0);
            acc[0][1] = __builtin_amdgcn_mfma_f32_16x16x32_bf16(a0, b1, acc[0][1], 0, 0, 0);
            acc[1][0] = __builtin_amdgcn_mfma_f32_16x16x32_bf16(a1, b0, acc[1][0], 0, 0, 0);
            acc[1][1] = __builtin_amdgcn_mfma_f32_16x16x32_bf16(a1, b1, acc[1][1], 0, 0, 0);
        }
        __syncthreads();
    }

    // epilogue: C/D layout col = lane&15, row = (lane>>4)*4 + reg  [m89]
    const int rbase = q * 4;
    #pragma unroll
    for (int mt = 0; mt < 2; ++mt) {
        #pragma unroll
        for (int nt = 0; nt < 2; ++nt) {
            #pragma unroll
            for (int r = 0; r < 4; ++r) {
                int row = m0 + wm + mt * 16 + rbase + r;
                int col = n0 + wn + nt * 16 + fr;
                C[row * OUT_DIM + col] = acc[mt][nt][r];
            }
        }
    }
}

// ---------------------------------------------------------------------------
extern "C" void kernel_launch(void* const* d_in, const int* in_sizes, int n_in,
                              void* d_out, int out_size, void* d_ws, size_t ws_size,
                              hipStream_t stream) {
    const float* x     = (const float*)d_in[0];
    const float* wb    = (const float*)d_in[1];
    const float* ws    = (const float*)d_in[2];
    const float* cps   = (const float*)d_in[3];
    const float* knots = (const float*)d_in[4];
    float* out = (float*)d_out;

    short* Abf = (short*)d_ws;                                     // 4 MB
    short* Btb = (short*)((char*)d_ws + (size_t)BATCH * KDIM * 2); // 0.5 MB

    prep_kernel<<<320, 256, 0, stream>>>(x, wb, ws, cps, knots, Abf, Btb);

    dim3 grid(OUT_DIM / BN, BATCH / BM);
    gemm_kernel<<<grid, 256, 0, stream>>>(Abf, Btb, out);
}